// Round 7
// baseline (295.029 us; speedup 1.0000x reference)
//
#include <hip/hip_runtime.h>

#define N_NODES 10000
#define N_EDGES 320000
#define NG      2
#define BATCH   4
#define F0      64
#define F1      128
#define F2      128
// z layout: [node][B*F0=256] bf16 (512 B/node). No h matrix: layer-2 done in
// u-space: u[ek][s][256] = sum_n r_ek[n] * z_s[n], q_ek = sum_s u W1c_s + S_ek b1.

__device__ __forceinline__ unsigned short f2bf(float x) {
    unsigned int u = __float_as_uint(x);
    unsigned int r = (u + 0x7fff + ((u >> 16) & 1)) >> 16;   // RNE
    return (unsigned short)r;
}
__device__ __forceinline__ float bflo(unsigned int u) { return __uint_as_float(u << 16); }
__device__ __forceinline__ float bfhi(unsigned int u) { return __uint_as_float(u & 0xffff0000u); }

// ---------------------------------------------------------------- pass 1 (fused)
// blocks [0,2500):    hist + slot(u16) + r1 + S1 + supp(r1) list + active push
// blocks [2500,12500): x[B,N,F0] fp32 -> z0[N,256] bf16
__global__ void histprep_kernel(const int* __restrict__ ei, const float* __restrict__ ev,
                                int* __restrict__ cnt, unsigned short* __restrict__ slot,
                                float* __restrict__ r1, float* __restrict__ S,
                                int* __restrict__ sup1, int* __restrict__ ns1,
                                int* __restrict__ aflag, int* __restrict__ list,
                                int* __restrict__ nact,
                                const float* __restrict__ x, unsigned short* __restrict__ z0) {
    int blk = blockIdx.x;
    if (blk < 2500) {
        int j = blk * 256 + threadIdx.x;
        if (j == 0) {       // force node 0 active (h0 needs z12[0], z22[0])
            if (atomicExch(&aflag[0], 1) == 0) { int p = atomicAdd(nact, 1); list[p] = 0; }
        }
        int e = j / N_EDGES, t = j - e * N_EDGES;
        int r = ei[e * 2 * N_EDGES + t];
        slot[j] = (unsigned short)atomicAdd(&cnt[e * N_NODES + r], 1);
        if (r == 0) {
            int c = ei[e * 2 * N_EDGES + N_EDGES + t];
            float v = ev[e * N_EDGES + t];
            float old = atomicAdd(&r1[e * N_NODES + c], v);
            atomicAdd(&S[e * 2], v);
            if (old == 0.f && v != 0.f) {
                int p = atomicAdd(&ns1[e], 1);
                sup1[e * N_NODES + p] = c;
                if (atomicExch(&aflag[c], 1) == 0) { int q = atomicAdd(nact, 1); list[q] = c; }
            }
        }
    } else {
        int idx = (blk - 2500) * 256 + threadIdx.x;   // covers N*B*F0 exactly
        int n = idx >> 8, rem = idx & 255, b = rem >> 6, f = rem & 63;
        z0[idx] = f2bf(x[b * (N_NODES * F0) + n * F0 + f]);
    }
}

// ---------------------------------------------------------------- pass 2: prefix scan
__global__ __launch_bounds__(1024) void prefix_kernel(const int* __restrict__ cnt,
                                                      int* __restrict__ rs) {
    __shared__ int wtot[16];
    int e = blockIdx.x, t = threadIdx.x;
    int lane = t & 63, w = t >> 6;
    int i0 = t * 10;
    int c[10];
    int local = 0;
    #pragma unroll
    for (int j = 0; j < 10; ++j) {
        int i = i0 + j;
        int v = (i < N_NODES) ? cnt[e * N_NODES + i] : 0;
        c[j] = local;
        local += v;
    }
    int inc = local;
    #pragma unroll
    for (int off = 1; off < 64; off <<= 1) {
        int u = __shfl_up(inc, off);
        if (lane >= off) inc += u;
    }
    if (lane == 63) wtot[w] = inc;
    __syncthreads();
    int base = 0;
    for (int k = 0; k < w; ++k) base += wtot[k];
    int excl = base + inc - local;
    #pragma unroll
    for (int j = 0; j < 10; ++j) {
        int i = i0 + j;
        if (i < N_NODES) rs[e * (N_NODES + 1) + i] = excl + c[j];
    }
    if (t == 1023) {
        int grand = 0;
        #pragma unroll
        for (int k = 0; k < 16; ++k) grand += wtot[k];
        rs[e * (N_NODES + 1) + N_NODES] = grand;
    }
}

// ---------------------------------------------------------------- pass 3: pure scatter
// packed 4 B entry: (bf16(val) << 16) | col
__global__ void scatter_kernel(const int* __restrict__ ei, const float* __restrict__ ev,
                               const int* __restrict__ rs, const unsigned short* __restrict__ slot,
                               unsigned int* __restrict__ cev) {
    int j = blockIdx.x * 256 + threadIdx.x;
    if (j >= NG * N_EDGES) return;
    int e = j / N_EDGES, t = j - e * N_EDGES;
    int r = ei[e * 2 * N_EDGES + t];
    int c = ei[e * 2 * N_EDGES + N_EDGES + t];
    float v = ev[e * N_EDGES + t];
    int pos = rs[e * (N_NODES + 1) + r] + (int)slot[j];
    cev[e * N_EDGES + pos] = ((unsigned int)f2bf(v) << 16) | (unsigned int)c;
}

// ---------------------------------------------------------------- pass 4: r2 via supp(r1) walk
// ~64 rows, ~2k edges total. Builds r2, S2, and completes the active list.
__global__ __launch_bounds__(256) void r2_kernel(const unsigned int* __restrict__ cev,
                                                 const int* __restrict__ rs,
                                                 const int* __restrict__ sup1,
                                                 const int* __restrict__ ns1,
                                                 const float* __restrict__ r1,
                                                 float* __restrict__ r2, float* __restrict__ S,
                                                 int* __restrict__ aflag, int* __restrict__ list,
                                                 int* __restrict__ nact) {
    int g = (blockIdx.x * 256 + threadIdx.x) >> 6;   // wave id, 64 waves
    int l = threadIdx.x & 63;
    int n0 = ns1[0], n1 = ns1[1];
    int total = n0 + n1;
    for (int idx = g; idx < total; idx += 64) {
        int e = (idx < n0) ? 0 : 1;
        int row = (idx < n0) ? sup1[idx] : sup1[N_NODES + idx - n0];
        float w = r1[e * N_NODES + row];
        int s    = rs[e * (N_NODES + 1) + row];
        int send = rs[e * (N_NODES + 1) + row + 1];
        for (int p = s + l; p < send; p += 64) {
            unsigned int u = cev[e * N_EDGES + p];
            int c = u & 0xffff;
            float add = w * bfhi(u);
            if (add != 0.f) {
                float old = atomicAdd(&r2[e * N_NODES + c], add);
                atomicAdd(&S[e * 2 + 1], add);
                if (old == 0.f) {
                    if (atomicExch(&aflag[c], 1) == 0) {
                        int q = atomicAdd(nact, 1);
                        list[q] = c;
                    }
                }
            }
        }
    }
}

// ---------------------------------------------------------------- SpMM tap-1 (full, half-split)
// 10000 blocks; half = 128 elems (2.56 MB working set, fits 4 MiB XCD L2).
// blockIdx%8<4 -> half 0 (XCDs 0-3 under round-robin dispatch), else half 1.
// wave = one (gso,row,half): 4 edge-slots x 16 lanes x 8 bf16.
__global__ __launch_bounds__(256) void spmm_full_kernel(
        const unsigned int* __restrict__ cev, const int* __restrict__ rs,
        const unsigned short* __restrict__ z0,
        unsigned short* __restrict__ z11, unsigned short* __restrict__ z21) {
    int blk = blockIdx.x;
    int m8 = blk & 7;
    int h = (m8 < 4) ? 0 : 1;
    int grp = (blk >> 3) * 4 + (m8 & 3);     // 0..4999 within this half
    int t = threadIdx.x;
    int w = t >> 6, l = t & 63;
    int rid = grp * 4 + w;                   // 0..19999
    int e = (rid >= N_NODES) ? 1 : 0;
    int i = rid - e * N_NODES;
    unsigned short* zout = e ? z21 : z11;
    const unsigned int* cv = cev + e * N_EDGES;
    int s    = rs[e * (N_NODES + 1) + i];
    int send = rs[e * (N_NODES + 1) + i + 1];
    int sl = l >> 4, li = l & 15;
    int eoff = h * 128 + li * 8;
    float acc[8];
    #pragma unroll
    for (int j = 0; j < 8; ++j) acc[j] = 0.f;

    int p = s + sl;
    for (; p + 4 < send; p += 8) {
        unsigned int u0 = cv[p];
        unsigned int u1 = cv[p + 4];
        int c0 = u0 & 0xffff; float v0 = bfhi(u0);
        int c1 = u1 & 0xffff; float v1 = bfhi(u1);
        uint4 za = *(const uint4*)&z0[c0 * 256 + eoff];
        uint4 zb = *(const uint4*)&z0[c1 * 256 + eoff];
        acc[0] += v0 * bflo(za.x) + v1 * bflo(zb.x);
        acc[1] += v0 * bfhi(za.x) + v1 * bfhi(zb.x);
        acc[2] += v0 * bflo(za.y) + v1 * bflo(zb.y);
        acc[3] += v0 * bfhi(za.y) + v1 * bfhi(zb.y);
        acc[4] += v0 * bflo(za.z) + v1 * bflo(zb.z);
        acc[5] += v0 * bfhi(za.z) + v1 * bfhi(zb.z);
        acc[6] += v0 * bflo(za.w) + v1 * bflo(zb.w);
        acc[7] += v0 * bfhi(za.w) + v1 * bfhi(zb.w);
    }
    for (; p < send; p += 4) {
        unsigned int u0 = cv[p];
        int c0 = u0 & 0xffff; float v0 = bfhi(u0);
        uint4 za = *(const uint4*)&z0[c0 * 256 + eoff];
        acc[0] += v0 * bflo(za.x); acc[1] += v0 * bfhi(za.x);
        acc[2] += v0 * bflo(za.y); acc[3] += v0 * bfhi(za.y);
        acc[4] += v0 * bflo(za.z); acc[5] += v0 * bfhi(za.z);
        acc[6] += v0 * bflo(za.w); acc[7] += v0 * bfhi(za.w);
    }
    // combine the 4 slot groups (lanes li, li+16, li+32, li+48 share elems)
    #pragma unroll
    for (int j = 0; j < 8; ++j) {
        acc[j] += __shfl_xor(acc[j], 16);
        acc[j] += __shfl_xor(acc[j], 32);
    }
    if (l < 16) {
        uint4 o;
        unsigned int r[8];
        #pragma unroll
        for (int j = 0; j < 8; ++j) r[j] = f2bf(acc[j]);
        o.x = r[0] | (r[1] << 16);
        o.y = r[2] | (r[3] << 16);
        o.z = r[4] | (r[5] << 16);
        o.w = r[6] | (r[7] << 16);
        *(uint4*)&zout[i * 256 + h * 128 + l * 8] = o;
    }
}

// ---------------------------------------------------------------- SpMM tap-2 (active rows only)
__global__ __launch_bounds__(256) void spmm_act_kernel(
        const unsigned int* __restrict__ cev, const int* __restrict__ rs,
        const unsigned short* __restrict__ zin0, const unsigned short* __restrict__ zin1,
        unsigned short* __restrict__ zout0, unsigned short* __restrict__ zout1,
        const int* __restrict__ list, const int* __restrict__ nact) {
    int t = threadIdx.x;
    int w = t >> 6, l = t & 63;
    int rid = blockIdx.x * 4 + w;
    int na = *nact;
    if (rid >= 2 * na) return;
    int e = (rid >= na) ? 1 : 0;
    int i = list[rid - e * na];
    const unsigned short* zin = e ? zin1 : zin0;
    unsigned short* zout = e ? zout1 : zout0;
    const unsigned int* cv = cev + e * N_EDGES;
    int s    = rs[e * (N_NODES + 1) + i];
    int send = rs[e * (N_NODES + 1) + i + 1];
    int hf = l >> 5, li = l & 31;
    float acc[8];
    #pragma unroll
    for (int j = 0; j < 8; ++j) acc[j] = 0.f;

    int p = s + hf;
    for (; p + 2 < send; p += 4) {
        unsigned int u0 = cv[p];
        unsigned int u1 = cv[p + 2];
        int c0 = u0 & 0xffff; float v0 = bfhi(u0);
        int c1 = u1 & 0xffff; float v1 = bfhi(u1);
        uint4 za = *(const uint4*)&zin[c0 * 256 + li * 8];
        uint4 zb = *(const uint4*)&zin[c1 * 256 + li * 8];
        acc[0] += v0 * bflo(za.x) + v1 * bflo(zb.x);
        acc[1] += v0 * bfhi(za.x) + v1 * bfhi(zb.x);
        acc[2] += v0 * bflo(za.y) + v1 * bflo(zb.y);
        acc[3] += v0 * bfhi(za.y) + v1 * bfhi(zb.y);
        acc[4] += v0 * bflo(za.z) + v1 * bflo(zb.z);
        acc[5] += v0 * bfhi(za.z) + v1 * bfhi(zb.z);
        acc[6] += v0 * bflo(za.w) + v1 * bflo(zb.w);
        acc[7] += v0 * bfhi(za.w) + v1 * bfhi(zb.w);
    }
    for (; p < send; p += 2) {
        unsigned int u0 = cv[p];
        int c0 = u0 & 0xffff; float v0 = bfhi(u0);
        uint4 za = *(const uint4*)&zin[c0 * 256 + li * 8];
        acc[0] += v0 * bflo(za.x); acc[1] += v0 * bfhi(za.x);
        acc[2] += v0 * bflo(za.y); acc[3] += v0 * bfhi(za.y);
        acc[4] += v0 * bflo(za.z); acc[5] += v0 * bfhi(za.z);
        acc[6] += v0 * bflo(za.w); acc[7] += v0 * bfhi(za.w);
    }
    #pragma unroll
    for (int j = 0; j < 8; ++j) acc[j] += __shfl_xor(acc[j], 32);
    if (hf == 0) {
        uint4 o;
        unsigned int r[8];
        #pragma unroll
        for (int j = 0; j < 8; ++j) r[j] = f2bf(acc[j]);
        o.x = r[0] | (r[1] << 16);
        o.y = r[2] | (r[3] << 16);
        o.z = r[4] | (r[5] << 16);
        o.w = r[6] | (r[7] << 16);
        *(uint4*)&zout[i * 256 + li * 8] = o;
    }
}

// ---------------------------------------------------------------- u-sums over active set
// u[ek*5+s][256] = sum_n r_ek[n] * z_s[n][:]   (ek: 0=(e0,k1) 1=(e0,k2) 2=(e1,k1) 3=(e1,k2))
__global__ __launch_bounds__(256) void u_kernel(
        const unsigned short* __restrict__ z0,  const unsigned short* __restrict__ z11,
        const unsigned short* __restrict__ z12, const unsigned short* __restrict__ z21,
        const unsigned short* __restrict__ z22,
        const float* __restrict__ r1, const float* __restrict__ r2,
        const int* __restrict__ list, const int* __restrict__ nact,
        float* __restrict__ u) {
    int t = threadIdx.x;          // elem 0..255
    int na = *nact;
    const unsigned short* Z[5] = { z0, z11, z12, z21, z22 };
    float acc[20];
    #pragma unroll
    for (int j = 0; j < 20; ++j) acc[j] = 0.f;
    for (int a = blockIdx.x; a < na; a += 32) {
        int n = list[a];
        float w0 = r1[n];
        float w1 = r2[n];
        float w2 = r1[N_NODES + n];
        float w3 = r2[N_NODES + n];
        #pragma unroll
        for (int s = 0; s < 5; ++s) {
            float zv = __uint_as_float(((unsigned int)Z[s][n * 256 + t]) << 16);
            acc[0 * 5 + s] += w0 * zv;
            acc[1 * 5 + s] += w1 * zv;
            acc[2 * 5 + s] += w2 * zv;
            acc[3 * 5 + s] += w3 * zv;
        }
    }
    #pragma unroll
    for (int j = 0; j < 20; ++j)
        if (acc[j] != 0.f) atomicAdd(&u[j * 256 + t], acc[j]);
}

// ---------------------------------------------------------------- final (1 block, 1024 thr)
// phase1: T[0][b][f1]=h0, T[1+ek][b][f1]=q_ek = sum_s u[ek][s]·W1c_s + S_ek·b1
// phase2: out[b][f2] = b2 + T[0]·(W2[00]+W2[10]) + T[1]·W2[01] + T[2]·W2[02]
//                         + T[3]·W2[11] + T[4]·W2[12]
__global__ __launch_bounds__(1024) void final_kernel(
        const unsigned short* __restrict__ z0,  const unsigned short* __restrict__ z11,
        const unsigned short* __restrict__ z12, const unsigned short* __restrict__ z21,
        const unsigned short* __restrict__ z22,
        const float* __restrict__ u, const float* __restrict__ S,
        const float* __restrict__ W1, const float* __restrict__ b1,
        const float* __restrict__ W2, const float* __restrict__ b2,
        float* __restrict__ out) {
    __shared__ float T[5 * 512];
    int tid = threadIdx.x;
    const unsigned short* Z[5] = { z0, z11, z12, z21, z22 };
    const int w1off[5] = { 0, 8192, 16384, 32768, 40960 };   // e0k1,e0k2 / e1k1,e1k2 (+e0k0/e1k0 for s=0)
    for (int o = tid; o < 2560; o += 1024) {
        int g = o >> 9, rem = o & 511;
        int b = rem >> 7, f1 = rem & 127;
        float acc;
        if (g == 0) {
            acc = b1[f1];
            #pragma unroll
            for (int s = 0; s < 5; ++s) {
                const unsigned short* zp = Z[s];
                for (int f0 = 0; f0 < 64; ++f0) {
                    float wv = W1[w1off[s] + f0 * 128 + f1];
                    if (s == 0) wv += W1[24576 + f0 * 128 + f1];
                    acc += __uint_as_float(((unsigned int)zp[b * 64 + f0]) << 16) * wv;
                }
            }
        } else {
            int ek = g - 1;
            acc = S[ek] * b1[f1];
            #pragma unroll
            for (int s = 0; s < 5; ++s) {
                const float* up = u + (ek * 5 + s) * 256 + b * 64;
                for (int f0 = 0; f0 < 64; ++f0) {
                    float wv = W1[w1off[s] + f0 * 128 + f1];
                    if (s == 0) wv += W1[24576 + f0 * 128 + f1];
                    acc += up[f0] * wv;
                }
            }
        }
        T[g * 512 + rem] = acc;
    }
    __syncthreads();
    if (tid < 512) {
        int b = tid >> 7, f2 = tid & 127;
        float acc = b2[f2];
        for (int f1 = 0; f1 < 128; ++f1) {
            int wi = f1 * 128 + f2;
            acc += T[0 * 512 + b * 128 + f1] * (W2[wi] + W2[3 * 16384 + wi]);
            acc += T[1 * 512 + b * 128 + f1] * W2[1 * 16384 + wi];
            acc += T[2 * 512 + b * 128 + f1] * W2[2 * 16384 + wi];
            acc += T[3 * 512 + b * 128 + f1] * W2[4 * 16384 + wi];
            acc += T[4 * 512 + b * 128 + f1] * W2[5 * 16384 + wi];
        }
        out[tid] = acc;
    }
}

// ----------------------------------------------------------------
extern "C" void kernel_launch(void* const* d_in, const int* in_sizes, int n_in,
                              void* d_out, int out_size, void* d_ws, size_t ws_size,
                              hipStream_t stream) {
    const float* x  = (const float*)d_in[0];
    const int*   ei = (const int*)d_in[1];
    const float* ev = (const float*)d_in[2];
    const float* W1 = (const float*)d_in[3];
    const float* b1 = (const float*)d_in[4];
    const float* W2 = (const float*)d_in[5];
    const float* b2 = (const float*)d_in[6];
    float* out = (float*)d_out;

    char* ws = (char*)d_ws;
    size_t off = 0;
    auto alloc = [&](size_t bytes) { size_t o = off; off += (bytes + 255) & ~(size_t)255; return o; };
    const size_t ZB  = (size_t)N_NODES * BATCH * F0 * 2;      // 5.12 MB per bf16 z buffer
    size_t o_z0   = alloc(ZB);
    size_t o_z11  = alloc(ZB);
    size_t o_z12  = alloc(ZB);
    size_t o_z21  = alloc(ZB);
    size_t o_z22  = alloc(ZB);
    size_t o_cev  = alloc((size_t)NG * N_EDGES * 4);          // packed (bf16 val | u16 col)
    size_t o_slot = alloc((size_t)NG * N_EDGES * 2);          // u16 slots
    size_t o_rs   = alloc((size_t)NG * (N_NODES + 1) * 4);
    size_t o_sup1 = alloc((size_t)NG * N_NODES * 4);
    size_t o_list = alloc((size_t)N_NODES * 4);
    size_t o_zero = off;                                      // zeroed region starts here
    size_t o_cnt   = alloc((size_t)NG * N_NODES * 4);
    size_t o_r     = alloc((size_t)2 * NG * N_NODES * 4);     // r1[2][N] then r2[2][N]
    size_t o_S     = alloc(4 * 4);                            // S1_e0, S2_e0, S1_e1, S2_e1
    size_t o_u     = alloc((size_t)20 * 256 * 4);
    size_t o_misc  = alloc(3 * 4);                            // ns1[2], nact
    size_t o_aflag = alloc((size_t)N_NODES * 4);
    size_t zero_bytes = off - o_zero;

    unsigned short* z0  = (unsigned short*)(ws + o_z0);
    unsigned short* z11 = (unsigned short*)(ws + o_z11);
    unsigned short* z12 = (unsigned short*)(ws + o_z12);
    unsigned short* z21 = (unsigned short*)(ws + o_z21);
    unsigned short* z22 = (unsigned short*)(ws + o_z22);
    unsigned int*   cev  = (unsigned int*)(ws + o_cev);
    unsigned short* slot = (unsigned short*)(ws + o_slot);
    int*   rs   = (int*)(ws + o_rs);
    int*   sup1 = (int*)(ws + o_sup1);
    int*   list = (int*)(ws + o_list);
    int*   cnt  = (int*)(ws + o_cnt);
    float* r1   = (float*)(ws + o_r);
    float* r2   = r1 + 2 * N_NODES;
    float* S    = (float*)(ws + o_S);
    float* u    = (float*)(ws + o_u);
    int*   ns1  = (int*)(ws + o_misc);
    int*   nact = ns1 + 2;
    int*   aflag = (int*)(ws + o_aflag);

    hipMemsetAsync(ws + o_zero, 0, zero_bytes, stream);

    histprep_kernel<<<12500, 256, 0, stream>>>(ei, ev, cnt, slot, r1, S, sup1, ns1,
                                               aflag, list, nact, x, z0);
    prefix_kernel  <<<2,    1024, 0, stream>>>(cnt, rs);
    scatter_kernel <<<2500,  256, 0, stream>>>(ei, ev, rs, slot, cev);
    r2_kernel      <<<16,    256, 0, stream>>>(cev, rs, sup1, ns1, r1, r2, S,
                                               aflag, list, nact);
    spmm_full_kernel<<<10000, 256, 0, stream>>>(cev, rs, z0, z11, z21);
    spmm_act_kernel<<<5000,  256, 0, stream>>>(cev, rs, z11, z21, z12, z22, list, nact);
    u_kernel       <<<32,    256, 0, stream>>>(z0, z11, z12, z21, z22, r1, r2, list, nact, u);
    final_kernel   <<<1,    1024, 0, stream>>>(z0, z11, z12, z21, z22, u, S, W1, b1, W2, b2, out);
}

// Round 8
// 271.343 us; speedup vs baseline: 1.0873x; 1.0873x over previous
//
#include <hip/hip_runtime.h>

#define N_NODES 10000
#define N_EDGES 320000
#define NG      2
#define BATCH   4
#define F0      64
#define F1      128
#define F2      128
// z layout: [node][B*F0=256] bf16 (512 B/node). No h matrix: layer-2 done in
// u-space: u[ek][s][256] = sum_n r_ek[n] * z_s[n], q_ek = sum_s u W1c_s + S_ek b1.

__device__ __forceinline__ unsigned short f2bf(float x) {
    unsigned int u = __float_as_uint(x);
    unsigned int r = (u + 0x7fff + ((u >> 16) & 1)) >> 16;   // RNE
    return (unsigned short)r;
}
__device__ __forceinline__ float bflo(unsigned int u) { return __uint_as_float(u << 16); }
__device__ __forceinline__ float bfhi(unsigned int u) { return __uint_as_float(u & 0xffff0000u); }

// ---------------------------------------------------------------- pass 1 (fused)
// blocks [0,2500):    hist + slot(u16) + r1 + S1 + supp(r1) list + active push
// blocks [2500,12500): x[B,N,F0] fp32 -> z0[N,256] bf16
__global__ void histprep_kernel(const int* __restrict__ ei, const float* __restrict__ ev,
                                int* __restrict__ cnt, unsigned short* __restrict__ slot,
                                float* __restrict__ r1, float* __restrict__ S,
                                int* __restrict__ sup1, int* __restrict__ ns1,
                                int* __restrict__ aflag, int* __restrict__ list,
                                int* __restrict__ nact,
                                const float* __restrict__ x, unsigned short* __restrict__ z0) {
    int blk = blockIdx.x;
    if (blk < 2500) {
        int j = blk * 256 + threadIdx.x;
        if (j == 0) {       // force node 0 active (h0 needs z12[0], z22[0])
            if (atomicExch(&aflag[0], 1) == 0) { int p = atomicAdd(nact, 1); list[p] = 0; }
        }
        int e = j / N_EDGES, t = j - e * N_EDGES;
        int r = ei[e * 2 * N_EDGES + t];
        slot[j] = (unsigned short)atomicAdd(&cnt[e * N_NODES + r], 1);
        if (r == 0) {
            int c = ei[e * 2 * N_EDGES + N_EDGES + t];
            float v = ev[e * N_EDGES + t];
            float old = atomicAdd(&r1[e * N_NODES + c], v);
            atomicAdd(&S[e * 2], v);
            if (old == 0.f && v != 0.f) {
                int p = atomicAdd(&ns1[e], 1);
                sup1[e * N_NODES + p] = c;
                if (atomicExch(&aflag[c], 1) == 0) { int q = atomicAdd(nact, 1); list[q] = c; }
            }
        }
    } else {
        int idx = (blk - 2500) * 256 + threadIdx.x;   // covers N*B*F0 exactly
        int n = idx >> 8, rem = idx & 255, b = rem >> 6, f = rem & 63;
        z0[idx] = f2bf(x[b * (N_NODES * F0) + n * F0 + f]);
    }
}

// ---------------------------------------------------------------- pass 2: prefix scan
__global__ __launch_bounds__(1024) void prefix_kernel(const int* __restrict__ cnt,
                                                      int* __restrict__ rs) {
    __shared__ int wtot[16];
    int e = blockIdx.x, t = threadIdx.x;
    int lane = t & 63, w = t >> 6;
    int i0 = t * 10;
    int c[10];
    int local = 0;
    #pragma unroll
    for (int j = 0; j < 10; ++j) {
        int i = i0 + j;
        int v = (i < N_NODES) ? cnt[e * N_NODES + i] : 0;
        c[j] = local;
        local += v;
    }
    int inc = local;
    #pragma unroll
    for (int off = 1; off < 64; off <<= 1) {
        int u = __shfl_up(inc, off);
        if (lane >= off) inc += u;
    }
    if (lane == 63) wtot[w] = inc;
    __syncthreads();
    int base = 0;
    for (int k = 0; k < w; ++k) base += wtot[k];
    int excl = base + inc - local;
    #pragma unroll
    for (int j = 0; j < 10; ++j) {
        int i = i0 + j;
        if (i < N_NODES) rs[e * (N_NODES + 1) + i] = excl + c[j];
    }
    if (t == 1023) {
        int grand = 0;
        #pragma unroll
        for (int k = 0; k < 16; ++k) grand += wtot[k];
        rs[e * (N_NODES + 1) + N_NODES] = grand;
    }
}

// ---------------------------------------------------------------- pass 3: pure scatter
// packed 4 B entry: (bf16(val) << 16) | col
__global__ void scatter_kernel(const int* __restrict__ ei, const float* __restrict__ ev,
                               const int* __restrict__ rs, const unsigned short* __restrict__ slot,
                               unsigned int* __restrict__ cev) {
    int j = blockIdx.x * 256 + threadIdx.x;
    if (j >= NG * N_EDGES) return;
    int e = j / N_EDGES, t = j - e * N_EDGES;
    int r = ei[e * 2 * N_EDGES + t];
    int c = ei[e * 2 * N_EDGES + N_EDGES + t];
    float v = ev[e * N_EDGES + t];
    int pos = rs[e * (N_NODES + 1) + r] + (int)slot[j];
    cev[e * N_EDGES + pos] = ((unsigned int)f2bf(v) << 16) | (unsigned int)c;
}

// ---------------------------------------------------------------- pass 4: r2 via supp(r1) walk
__global__ __launch_bounds__(256) void r2_kernel(const unsigned int* __restrict__ cev,
                                                 const int* __restrict__ rs,
                                                 const int* __restrict__ sup1,
                                                 const int* __restrict__ ns1,
                                                 const float* __restrict__ r1,
                                                 float* __restrict__ r2, float* __restrict__ S,
                                                 int* __restrict__ aflag, int* __restrict__ list,
                                                 int* __restrict__ nact) {
    int g = (blockIdx.x * 256 + threadIdx.x) >> 6;   // wave id, 64 waves
    int l = threadIdx.x & 63;
    int n0 = ns1[0], n1 = ns1[1];
    int total = n0 + n1;
    for (int idx = g; idx < total; idx += 64) {
        int e = (idx < n0) ? 0 : 1;
        int row = (idx < n0) ? sup1[idx] : sup1[N_NODES + idx - n0];
        float w = r1[e * N_NODES + row];
        int s    = rs[e * (N_NODES + 1) + row];
        int send = rs[e * (N_NODES + 1) + row + 1];
        for (int p = s + l; p < send; p += 64) {
            unsigned int u = cev[e * N_EDGES + p];
            int c = u & 0xffff;
            float add = w * bfhi(u);
            if (add != 0.f) {
                float old = atomicAdd(&r2[e * N_NODES + c], add);
                atomicAdd(&S[e * 2 + 1], add);
                if (old == 0.f) {
                    if (atomicExch(&aflag[c], 1) == 0) {
                        int q = atomicAdd(nact, 1);
                        list[q] = c;
                    }
                }
            }
        }
    }
}

// ---------------------------------------------------------------- SpMM tap-1 (full, half-split)
__global__ __launch_bounds__(256) void spmm_full_kernel(
        const unsigned int* __restrict__ cev, const int* __restrict__ rs,
        const unsigned short* __restrict__ z0,
        unsigned short* __restrict__ z11, unsigned short* __restrict__ z21) {
    int blk = blockIdx.x;
    int m8 = blk & 7;
    int h = (m8 < 4) ? 0 : 1;
    int grp = (blk >> 3) * 4 + (m8 & 3);     // 0..4999 within this half
    int t = threadIdx.x;
    int w = t >> 6, l = t & 63;
    int rid = grp * 4 + w;                   // 0..19999
    int e = (rid >= N_NODES) ? 1 : 0;
    int i = rid - e * N_NODES;
    unsigned short* zout = e ? z21 : z11;
    const unsigned int* cv = cev + e * N_EDGES;
    int s    = rs[e * (N_NODES + 1) + i];
    int send = rs[e * (N_NODES + 1) + i + 1];
    int sl = l >> 4, li = l & 15;
    int eoff = h * 128 + li * 8;
    float acc[8];
    #pragma unroll
    for (int j = 0; j < 8; ++j) acc[j] = 0.f;

    int p = s + sl;
    for (; p + 4 < send; p += 8) {
        unsigned int u0 = cv[p];
        unsigned int u1 = cv[p + 4];
        int c0 = u0 & 0xffff; float v0 = bfhi(u0);
        int c1 = u1 & 0xffff; float v1 = bfhi(u1);
        uint4 za = *(const uint4*)&z0[c0 * 256 + eoff];
        uint4 zb = *(const uint4*)&z0[c1 * 256 + eoff];
        acc[0] += v0 * bflo(za.x) + v1 * bflo(zb.x);
        acc[1] += v0 * bfhi(za.x) + v1 * bfhi(zb.x);
        acc[2] += v0 * bflo(za.y) + v1 * bflo(zb.y);
        acc[3] += v0 * bfhi(za.y) + v1 * bfhi(zb.y);
        acc[4] += v0 * bflo(za.z) + v1 * bflo(zb.z);
        acc[5] += v0 * bfhi(za.z) + v1 * bfhi(zb.z);
        acc[6] += v0 * bflo(za.w) + v1 * bflo(zb.w);
        acc[7] += v0 * bfhi(za.w) + v1 * bfhi(zb.w);
    }
    for (; p < send; p += 4) {
        unsigned int u0 = cv[p];
        int c0 = u0 & 0xffff; float v0 = bfhi(u0);
        uint4 za = *(const uint4*)&z0[c0 * 256 + eoff];
        acc[0] += v0 * bflo(za.x); acc[1] += v0 * bfhi(za.x);
        acc[2] += v0 * bflo(za.y); acc[3] += v0 * bfhi(za.y);
        acc[4] += v0 * bflo(za.z); acc[5] += v0 * bfhi(za.z);
        acc[6] += v0 * bflo(za.w); acc[7] += v0 * bfhi(za.w);
    }
    #pragma unroll
    for (int j = 0; j < 8; ++j) {
        acc[j] += __shfl_xor(acc[j], 16);
        acc[j] += __shfl_xor(acc[j], 32);
    }
    if (l < 16) {
        uint4 o;
        unsigned int r[8];
        #pragma unroll
        for (int j = 0; j < 8; ++j) r[j] = f2bf(acc[j]);
        o.x = r[0] | (r[1] << 16);
        o.y = r[2] | (r[3] << 16);
        o.z = r[4] | (r[5] << 16);
        o.w = r[6] | (r[7] << 16);
        *(uint4*)&zout[i * 256 + h * 128 + l * 8] = o;
    }
}

// ---------------------------------------------------------------- SpMM tap-2 (active rows only)
__global__ __launch_bounds__(256) void spmm_act_kernel(
        const unsigned int* __restrict__ cev, const int* __restrict__ rs,
        const unsigned short* __restrict__ zin0, const unsigned short* __restrict__ zin1,
        unsigned short* __restrict__ zout0, unsigned short* __restrict__ zout1,
        const int* __restrict__ list, const int* __restrict__ nact) {
    int t = threadIdx.x;
    int w = t >> 6, l = t & 63;
    int rid = blockIdx.x * 4 + w;
    int na = *nact;
    if (rid >= 2 * na) return;
    int e = (rid >= na) ? 1 : 0;
    int i = list[rid - e * na];
    const unsigned short* zin = e ? zin1 : zin0;
    unsigned short* zout = e ? zout1 : zout0;
    const unsigned int* cv = cev + e * N_EDGES;
    int s    = rs[e * (N_NODES + 1) + i];
    int send = rs[e * (N_NODES + 1) + i + 1];
    int hf = l >> 5, li = l & 31;
    float acc[8];
    #pragma unroll
    for (int j = 0; j < 8; ++j) acc[j] = 0.f;

    int p = s + hf;
    for (; p + 2 < send; p += 4) {
        unsigned int u0 = cv[p];
        unsigned int u1 = cv[p + 2];
        int c0 = u0 & 0xffff; float v0 = bfhi(u0);
        int c1 = u1 & 0xffff; float v1 = bfhi(u1);
        uint4 za = *(const uint4*)&zin[c0 * 256 + li * 8];
        uint4 zb = *(const uint4*)&zin[c1 * 256 + li * 8];
        acc[0] += v0 * bflo(za.x) + v1 * bflo(zb.x);
        acc[1] += v0 * bfhi(za.x) + v1 * bfhi(zb.x);
        acc[2] += v0 * bflo(za.y) + v1 * bflo(zb.y);
        acc[3] += v0 * bfhi(za.y) + v1 * bfhi(zb.y);
        acc[4] += v0 * bflo(za.z) + v1 * bflo(zb.z);
        acc[5] += v0 * bfhi(za.z) + v1 * bfhi(zb.z);
        acc[6] += v0 * bflo(za.w) + v1 * bflo(zb.w);
        acc[7] += v0 * bfhi(za.w) + v1 * bfhi(zb.w);
    }
    for (; p < send; p += 2) {
        unsigned int u0 = cv[p];
        int c0 = u0 & 0xffff; float v0 = bfhi(u0);
        uint4 za = *(const uint4*)&zin[c0 * 256 + li * 8];
        acc[0] += v0 * bflo(za.x); acc[1] += v0 * bfhi(za.x);
        acc[2] += v0 * bflo(za.y); acc[3] += v0 * bfhi(za.y);
        acc[4] += v0 * bflo(za.z); acc[5] += v0 * bfhi(za.z);
        acc[6] += v0 * bflo(za.w); acc[7] += v0 * bfhi(za.w);
    }
    #pragma unroll
    for (int j = 0; j < 8; ++j) acc[j] += __shfl_xor(acc[j], 32);
    if (hf == 0) {
        uint4 o;
        unsigned int r[8];
        #pragma unroll
        for (int j = 0; j < 8; ++j) r[j] = f2bf(acc[j]);
        o.x = r[0] | (r[1] << 16);
        o.y = r[2] | (r[3] << 16);
        o.z = r[4] | (r[5] << 16);
        o.w = r[6] | (r[7] << 16);
        *(uint4*)&zout[i * 256 + li * 8] = o;
    }
}

// ---------------------------------------------------------------- u-sums over active set
__global__ __launch_bounds__(256) void u_kernel(
        const unsigned short* __restrict__ z0,  const unsigned short* __restrict__ z11,
        const unsigned short* __restrict__ z12, const unsigned short* __restrict__ z21,
        const unsigned short* __restrict__ z22,
        const float* __restrict__ r1, const float* __restrict__ r2,
        const int* __restrict__ list, const int* __restrict__ nact,
        float* __restrict__ u) {
    int t = threadIdx.x;          // elem 0..255
    int na = *nact;
    const unsigned short* Z[5] = { z0, z11, z12, z21, z22 };
    float acc[20];
    #pragma unroll
    for (int j = 0; j < 20; ++j) acc[j] = 0.f;
    for (int a = blockIdx.x; a < na; a += 64) {
        int n = list[a];
        float w0 = r1[n];
        float w1 = r2[n];
        float w2 = r1[N_NODES + n];
        float w3 = r2[N_NODES + n];
        #pragma unroll
        for (int s = 0; s < 5; ++s) {
            float zv = __uint_as_float(((unsigned int)Z[s][n * 256 + t]) << 16);
            acc[0 * 5 + s] += w0 * zv;
            acc[1 * 5 + s] += w1 * zv;
            acc[2 * 5 + s] += w2 * zv;
            acc[3 * 5 + s] += w3 * zv;
        }
    }
    #pragma unroll
    for (int j = 0; j < 20; ++j)
        if (acc[j] != 0.f) atomicAdd(&u[j * 256 + t], acc[j]);
}

// ---------------------------------------------------------------- final stage 1 (parallel)
// thread = (s, g, b, f1): 5*5*4*128 = 12800 threads. T[g][b][f1] += dot_64(f0).
// g=0: h0 from z_s[node0]; g=1..4: q_ek from u. W1 reads coalesced across f1.
__global__ __launch_bounds__(256) void final_T_kernel(
        const unsigned short* __restrict__ z0,  const unsigned short* __restrict__ z11,
        const unsigned short* __restrict__ z12, const unsigned short* __restrict__ z21,
        const unsigned short* __restrict__ z22,
        const float* __restrict__ u, const float* __restrict__ S,
        const float* __restrict__ W1, const float* __restrict__ b1,
        float* __restrict__ T) {
    int idx = blockIdx.x * 256 + threadIdx.x;   // 50*256 = 12800 exactly
    int s = idx / 2560;
    int o = idx - s * 2560;
    int g = o >> 9, rem = o & 511;
    int b = rem >> 7, f1 = rem & 127;
    const unsigned short* Z[5] = { z0, z11, z12, z21, z22 };
    const int w1off[5] = { 0, 8192, 16384, 32768, 40960 };
    const float* Wp  = W1 + w1off[s] + f1;
    const float* Wp0 = W1 + 24576 + f1;         // W1[1,0] (added into s=0)
    float acc = 0.f;
    if (g == 0) {
        const unsigned short* zp = Z[s] + b * 64;
        #pragma unroll 8
        for (int f0 = 0; f0 < 64; ++f0) {
            float wv = Wp[f0 * 128];
            if (s == 0) wv += Wp0[f0 * 128];
            acc += __uint_as_float(((unsigned int)zp[f0]) << 16) * wv;
        }
        if (s == 0) acc += b1[f1];
    } else {
        int ek = g - 1;
        const float* up = u + (ek * 5 + s) * 256 + b * 64;
        #pragma unroll 8
        for (int f0 = 0; f0 < 64; ++f0) {
            float wv = Wp[f0 * 128];
            if (s == 0) wv += Wp0[f0 * 128];
            acc += up[f0] * wv;
        }
        if (s == 0) acc += S[ek] * b1[f1];
    }
    atomicAdd(&T[o], acc);
}

// ---------------------------------------------------------------- final stage 2 (parallel)
// thread = (g, b, f2): 5*4*128 = 2560. out[b][f2] += dot_128(f1) over T[g].
__global__ __launch_bounds__(256) void final_out_kernel(
        const float* __restrict__ T, const float* __restrict__ W2,
        const float* __restrict__ b2, float* __restrict__ out) {
    int idx = blockIdx.x * 256 + threadIdx.x;   // 10*256 = 2560 exactly
    int g = idx / 512;
    int rem = idx - g * 512;
    int b = rem >> 7, f2 = rem & 127;
    const int w2off[5] = { 0, 16384, 32768, 65536, 81920 };  // W2[00],[01],[02],[11],[12]
    const float* Wp  = W2 + w2off[g] + f2;
    const float* Wp0 = W2 + 3 * 16384 + f2;     // W2[1,0] (added into g=0)
    const float* Tp  = T + g * 512 + b * 128;
    float acc = (g == 0) ? b2[f2] : 0.f;
    #pragma unroll 8
    for (int f1 = 0; f1 < 128; ++f1) {
        float wv = Wp[f1 * 128];
        if (g == 0) wv += Wp0[f1 * 128];
        acc += Tp[f1] * wv;
    }
    atomicAdd(&out[rem], acc);
}

// ----------------------------------------------------------------
extern "C" void kernel_launch(void* const* d_in, const int* in_sizes, int n_in,
                              void* d_out, int out_size, void* d_ws, size_t ws_size,
                              hipStream_t stream) {
    const float* x  = (const float*)d_in[0];
    const int*   ei = (const int*)d_in[1];
    const float* ev = (const float*)d_in[2];
    const float* W1 = (const float*)d_in[3];
    const float* b1 = (const float*)d_in[4];
    const float* W2 = (const float*)d_in[5];
    const float* b2 = (const float*)d_in[6];
    float* out = (float*)d_out;

    char* ws = (char*)d_ws;
    size_t off = 0;
    auto alloc = [&](size_t bytes) { size_t o = off; off += (bytes + 255) & ~(size_t)255; return o; };
    const size_t ZB  = (size_t)N_NODES * BATCH * F0 * 2;      // 5.12 MB per bf16 z buffer
    size_t o_z0   = alloc(ZB);
    size_t o_z11  = alloc(ZB);
    size_t o_z12  = alloc(ZB);
    size_t o_z21  = alloc(ZB);
    size_t o_z22  = alloc(ZB);
    size_t o_cev  = alloc((size_t)NG * N_EDGES * 4);          // packed (bf16 val | u16 col)
    size_t o_slot = alloc((size_t)NG * N_EDGES * 2);          // u16 slots
    size_t o_rs   = alloc((size_t)NG * (N_NODES + 1) * 4);
    size_t o_sup1 = alloc((size_t)NG * N_NODES * 4);
    size_t o_list = alloc((size_t)N_NODES * 4);
    size_t o_zero = off;                                      // zeroed region starts here
    size_t o_cnt   = alloc((size_t)NG * N_NODES * 4);
    size_t o_r     = alloc((size_t)2 * NG * N_NODES * 4);     // r1[2][N] then r2[2][N]
    size_t o_S     = alloc(4 * 4);                            // S1_e0, S2_e0, S1_e1, S2_e1
    size_t o_u     = alloc((size_t)20 * 256 * 4);
    size_t o_T     = alloc((size_t)5 * 512 * 4);
    size_t o_misc  = alloc(3 * 4);                            // ns1[2], nact
    size_t o_aflag = alloc((size_t)N_NODES * 4);
    size_t zero_bytes = off - o_zero;

    unsigned short* z0  = (unsigned short*)(ws + o_z0);
    unsigned short* z11 = (unsigned short*)(ws + o_z11);
    unsigned short* z12 = (unsigned short*)(ws + o_z12);
    unsigned short* z21 = (unsigned short*)(ws + o_z21);
    unsigned short* z22 = (unsigned short*)(ws + o_z22);
    unsigned int*   cev  = (unsigned int*)(ws + o_cev);
    unsigned short* slot = (unsigned short*)(ws + o_slot);
    int*   rs   = (int*)(ws + o_rs);
    int*   sup1 = (int*)(ws + o_sup1);
    int*   list = (int*)(ws + o_list);
    int*   cnt  = (int*)(ws + o_cnt);
    float* r1   = (float*)(ws + o_r);
    float* r2   = r1 + 2 * N_NODES;
    float* S    = (float*)(ws + o_S);
    float* u    = (float*)(ws + o_u);
    float* T    = (float*)(ws + o_T);
    int*   ns1  = (int*)(ws + o_misc);
    int*   nact = ns1 + 2;
    int*   aflag = (int*)(ws + o_aflag);

    hipMemsetAsync(ws + o_zero, 0, zero_bytes, stream);
    hipMemsetAsync(out, 0, 512 * sizeof(float), stream);

    histprep_kernel<<<12500, 256, 0, stream>>>(ei, ev, cnt, slot, r1, S, sup1, ns1,
                                               aflag, list, nact, x, z0);
    prefix_kernel  <<<2,    1024, 0, stream>>>(cnt, rs);
    scatter_kernel <<<2500,  256, 0, stream>>>(ei, ev, rs, slot, cev);
    r2_kernel      <<<16,    256, 0, stream>>>(cev, rs, sup1, ns1, r1, r2, S,
                                               aflag, list, nact);
    spmm_full_kernel<<<10000, 256, 0, stream>>>(cev, rs, z0, z11, z21);
    spmm_act_kernel<<<5000,  256, 0, stream>>>(cev, rs, z11, z21, z12, z22, list, nact);
    u_kernel       <<<64,    256, 0, stream>>>(z0, z11, z12, z21, z22, r1, r2, list, nact, u);
    final_T_kernel <<<50,    256, 0, stream>>>(z0, z11, z12, z21, z22, u, S, W1, b1, T);
    final_out_kernel<<<10,   256, 0, stream>>>(T, W2, b2, out);
}

// Round 9
// 229.520 us; speedup vs baseline: 1.2854x; 1.1822x over previous
//
#include <hip/hip_runtime.h>

#define N_NODES 10000
#define N_EDGES 320000
#define NG      2
#define BATCH   4
#define F0      64
#define F1      128
#define F2      128
// z layout: [node][B*F0=256] bf16 (512 B/node). No h matrix: layer-2 done in
// u-space: u[ek][s][256] = sum_n r_ek[n] * z_s[n], q_ek = sum_s u W1c_s + S_ek b1.

__device__ __forceinline__ unsigned short f2bf(float x) {
    unsigned int u = __float_as_uint(x);
    unsigned int r = (u + 0x7fff + ((u >> 16) & 1)) >> 16;   // RNE
    return (unsigned short)r;
}
__device__ __forceinline__ float bflo(unsigned int u) { return __uint_as_float(u << 16); }
__device__ __forceinline__ float bfhi(unsigned int u) { return __uint_as_float(u & 0xffff0000u); }

// ---------------------------------------------------------------- pass 1 (fused)
// blocks [0,2500):    hist + slot(u16) + r1 + S1 + supp(r1) list + active push
// blocks [2500,12500): x[B,N,F0] fp32 -> z0[N,256] bf16
__global__ void histprep_kernel(const int* __restrict__ ei, const float* __restrict__ ev,
                                int* __restrict__ cnt, unsigned short* __restrict__ slot,
                                float* __restrict__ r1, float* __restrict__ S,
                                int* __restrict__ sup1, int* __restrict__ ns1,
                                int* __restrict__ aflag, int* __restrict__ list,
                                int* __restrict__ nact,
                                const float* __restrict__ x, unsigned short* __restrict__ z0) {
    int blk = blockIdx.x;
    if (blk < 2500) {
        int j = blk * 256 + threadIdx.x;
        if (j == 0) {       // force node 0 active (h0 needs z12[0], z22[0])
            if (atomicExch(&aflag[0], 1) == 0) { int p = atomicAdd(nact, 1); list[p] = 0; }
        }
        int e = j / N_EDGES, t = j - e * N_EDGES;
        int r = ei[e * 2 * N_EDGES + t];
        slot[j] = (unsigned short)atomicAdd(&cnt[e * N_NODES + r], 1);
        if (r == 0) {
            int c = ei[e * 2 * N_EDGES + N_EDGES + t];
            float v = ev[e * N_EDGES + t];
            float old = atomicAdd(&r1[e * N_NODES + c], v);
            atomicAdd(&S[e * 2], v);
            if (old == 0.f && v != 0.f) {
                int p = atomicAdd(&ns1[e], 1);
                sup1[e * N_NODES + p] = c;
                if (atomicExch(&aflag[c], 1) == 0) { int q = atomicAdd(nact, 1); list[q] = c; }
            }
        }
    } else {
        int idx = (blk - 2500) * 256 + threadIdx.x;   // covers N*B*F0 exactly
        int n = idx >> 8, rem = idx & 255, b = rem >> 6, f = rem & 63;
        z0[idx] = f2bf(x[b * (N_NODES * F0) + n * F0 + f]);
    }
}

// ---------------------------------------------------------------- pass 2: prefix scan
__global__ __launch_bounds__(1024) void prefix_kernel(const int* __restrict__ cnt,
                                                      int* __restrict__ rs) {
    __shared__ int wtot[16];
    int e = blockIdx.x, t = threadIdx.x;
    int lane = t & 63, w = t >> 6;
    int i0 = t * 10;
    int c[10];
    int local = 0;
    #pragma unroll
    for (int j = 0; j < 10; ++j) {
        int i = i0 + j;
        int v = (i < N_NODES) ? cnt[e * N_NODES + i] : 0;
        c[j] = local;
        local += v;
    }
    int inc = local;
    #pragma unroll
    for (int off = 1; off < 64; off <<= 1) {
        int u = __shfl_up(inc, off);
        if (lane >= off) inc += u;
    }
    if (lane == 63) wtot[w] = inc;
    __syncthreads();
    int base = 0;
    for (int k = 0; k < w; ++k) base += wtot[k];
    int excl = base + inc - local;
    #pragma unroll
    for (int j = 0; j < 10; ++j) {
        int i = i0 + j;
        if (i < N_NODES) rs[e * (N_NODES + 1) + i] = excl + c[j];
    }
    if (t == 1023) {
        int grand = 0;
        #pragma unroll
        for (int k = 0; k < 16; ++k) grand += wtot[k];
        rs[e * (N_NODES + 1) + N_NODES] = grand;
    }
}

// ---------------------------------------------------------------- pass 3: pure scatter
// packed 4 B entry: (bf16(val) << 16) | col
__global__ void scatter_kernel(const int* __restrict__ ei, const float* __restrict__ ev,
                               const int* __restrict__ rs, const unsigned short* __restrict__ slot,
                               unsigned int* __restrict__ cev) {
    int j = blockIdx.x * 256 + threadIdx.x;
    if (j >= NG * N_EDGES) return;
    int e = j / N_EDGES, t = j - e * N_EDGES;
    int r = ei[e * 2 * N_EDGES + t];
    int c = ei[e * 2 * N_EDGES + N_EDGES + t];
    float v = ev[e * N_EDGES + t];
    int pos = rs[e * (N_NODES + 1) + r] + (int)slot[j];
    cev[e * N_EDGES + pos] = ((unsigned int)f2bf(v) << 16) | (unsigned int)c;
}

// ---------------------------------------------------------------- pass 4: r2 via supp(r1) walk
__global__ __launch_bounds__(256) void r2_kernel(const unsigned int* __restrict__ cev,
                                                 const int* __restrict__ rs,
                                                 const int* __restrict__ sup1,
                                                 const int* __restrict__ ns1,
                                                 const float* __restrict__ r1,
                                                 float* __restrict__ r2, float* __restrict__ S,
                                                 int* __restrict__ aflag, int* __restrict__ list,
                                                 int* __restrict__ nact) {
    int g = (blockIdx.x * 256 + threadIdx.x) >> 6;   // wave id, 64 waves
    int l = threadIdx.x & 63;
    int n0 = ns1[0], n1 = ns1[1];
    int total = n0 + n1;
    for (int idx = g; idx < total; idx += 64) {
        int e = (idx < n0) ? 0 : 1;
        int row = (idx < n0) ? sup1[idx] : sup1[N_NODES + idx - n0];
        float w = r1[e * N_NODES + row];
        int s    = rs[e * (N_NODES + 1) + row];
        int send = rs[e * (N_NODES + 1) + row + 1];
        for (int p = s + l; p < send; p += 64) {
            unsigned int u = cev[e * N_EDGES + p];
            int c = u & 0xffff;
            float add = w * bfhi(u);
            if (add != 0.f) {
                float old = atomicAdd(&r2[e * N_NODES + c], add);
                atomicAdd(&S[e * 2 + 1], add);
                if (old == 0.f) {
                    if (atomicExch(&aflag[c], 1) == 0) {
                        int q = atomicAdd(nact, 1);
                        list[q] = c;
                    }
                }
            }
        }
    }
}

// ---------------------------------------------------------------- SpMM tap-1 (full, half-split)
__global__ __launch_bounds__(256) void spmm_full_kernel(
        const unsigned int* __restrict__ cev, const int* __restrict__ rs,
        const unsigned short* __restrict__ z0,
        unsigned short* __restrict__ z11, unsigned short* __restrict__ z21) {
    int blk = blockIdx.x;
    int m8 = blk & 7;
    int h = (m8 < 4) ? 0 : 1;
    int grp = (blk >> 3) * 4 + (m8 & 3);     // 0..4999 within this half
    int t = threadIdx.x;
    int w = t >> 6, l = t & 63;
    int rid = grp * 4 + w;                   // 0..19999
    int e = (rid >= N_NODES) ? 1 : 0;
    int i = rid - e * N_NODES;
    unsigned short* zout = e ? z21 : z11;
    const unsigned int* cv = cev + e * N_EDGES;
    int s    = rs[e * (N_NODES + 1) + i];
    int send = rs[e * (N_NODES + 1) + i + 1];
    int sl = l >> 4, li = l & 15;
    int eoff = h * 128 + li * 8;
    float acc[8];
    #pragma unroll
    for (int j = 0; j < 8; ++j) acc[j] = 0.f;

    int p = s + sl;
    for (; p + 4 < send; p += 8) {
        unsigned int u0 = cv[p];
        unsigned int u1 = cv[p + 4];
        int c0 = u0 & 0xffff; float v0 = bfhi(u0);
        int c1 = u1 & 0xffff; float v1 = bfhi(u1);
        uint4 za = *(const uint4*)&z0[c0 * 256 + eoff];
        uint4 zb = *(const uint4*)&z0[c1 * 256 + eoff];
        acc[0] += v0 * bflo(za.x) + v1 * bflo(zb.x);
        acc[1] += v0 * bfhi(za.x) + v1 * bfhi(zb.x);
        acc[2] += v0 * bflo(za.y) + v1 * bflo(zb.y);
        acc[3] += v0 * bfhi(za.y) + v1 * bfhi(zb.y);
        acc[4] += v0 * bflo(za.z) + v1 * bflo(zb.z);
        acc[5] += v0 * bfhi(za.z) + v1 * bfhi(zb.z);
        acc[6] += v0 * bflo(za.w) + v1 * bflo(zb.w);
        acc[7] += v0 * bfhi(za.w) + v1 * bfhi(zb.w);
    }
    for (; p < send; p += 4) {
        unsigned int u0 = cv[p];
        int c0 = u0 & 0xffff; float v0 = bfhi(u0);
        uint4 za = *(const uint4*)&z0[c0 * 256 + eoff];
        acc[0] += v0 * bflo(za.x); acc[1] += v0 * bfhi(za.x);
        acc[2] += v0 * bflo(za.y); acc[3] += v0 * bfhi(za.y);
        acc[4] += v0 * bflo(za.z); acc[5] += v0 * bfhi(za.z);
        acc[6] += v0 * bflo(za.w); acc[7] += v0 * bfhi(za.w);
    }
    #pragma unroll
    for (int j = 0; j < 8; ++j) {
        acc[j] += __shfl_xor(acc[j], 16);
        acc[j] += __shfl_xor(acc[j], 32);
    }
    if (l < 16) {
        uint4 o;
        unsigned int r[8];
        #pragma unroll
        for (int j = 0; j < 8; ++j) r[j] = f2bf(acc[j]);
        o.x = r[0] | (r[1] << 16);
        o.y = r[2] | (r[3] << 16);
        o.z = r[4] | (r[5] << 16);
        o.w = r[6] | (r[7] << 16);
        *(uint4*)&zout[i * 256 + h * 128 + l * 8] = o;
    }
}

// ---------------------------------------------------------------- SpMM tap-2 (active rows only)
__global__ __launch_bounds__(256) void spmm_act_kernel(
        const unsigned int* __restrict__ cev, const int* __restrict__ rs,
        const unsigned short* __restrict__ zin0, const unsigned short* __restrict__ zin1,
        unsigned short* __restrict__ zout0, unsigned short* __restrict__ zout1,
        const int* __restrict__ list, const int* __restrict__ nact) {
    int t = threadIdx.x;
    int w = t >> 6, l = t & 63;
    int rid = blockIdx.x * 4 + w;
    int na = *nact;
    if (rid >= 2 * na) return;
    int e = (rid >= na) ? 1 : 0;
    int i = list[rid - e * na];
    const unsigned short* zin = e ? zin1 : zin0;
    unsigned short* zout = e ? zout1 : zout0;
    const unsigned int* cv = cev + e * N_EDGES;
    int s    = rs[e * (N_NODES + 1) + i];
    int send = rs[e * (N_NODES + 1) + i + 1];
    int hf = l >> 5, li = l & 31;
    float acc[8];
    #pragma unroll
    for (int j = 0; j < 8; ++j) acc[j] = 0.f;

    int p = s + hf;
    for (; p + 2 < send; p += 4) {
        unsigned int u0 = cv[p];
        unsigned int u1 = cv[p + 2];
        int c0 = u0 & 0xffff; float v0 = bfhi(u0);
        int c1 = u1 & 0xffff; float v1 = bfhi(u1);
        uint4 za = *(const uint4*)&zin[c0 * 256 + li * 8];
        uint4 zb = *(const uint4*)&zin[c1 * 256 + li * 8];
        acc[0] += v0 * bflo(za.x) + v1 * bflo(zb.x);
        acc[1] += v0 * bfhi(za.x) + v1 * bfhi(zb.x);
        acc[2] += v0 * bflo(za.y) + v1 * bflo(zb.y);
        acc[3] += v0 * bfhi(za.y) + v1 * bfhi(zb.y);
        acc[4] += v0 * bflo(za.z) + v1 * bflo(zb.z);
        acc[5] += v0 * bfhi(za.z) + v1 * bfhi(zb.z);
        acc[6] += v0 * bflo(za.w) + v1 * bflo(zb.w);
        acc[7] += v0 * bfhi(za.w) + v1 * bfhi(zb.w);
    }
    for (; p < send; p += 2) {
        unsigned int u0 = cv[p];
        int c0 = u0 & 0xffff; float v0 = bfhi(u0);
        uint4 za = *(const uint4*)&zin[c0 * 256 + li * 8];
        acc[0] += v0 * bflo(za.x); acc[1] += v0 * bfhi(za.x);
        acc[2] += v0 * bflo(za.y); acc[3] += v0 * bfhi(za.y);
        acc[4] += v0 * bflo(za.z); acc[5] += v0 * bfhi(za.z);
        acc[6] += v0 * bflo(za.w); acc[7] += v0 * bfhi(za.w);
    }
    #pragma unroll
    for (int j = 0; j < 8; ++j) acc[j] += __shfl_xor(acc[j], 32);
    if (hf == 0) {
        uint4 o;
        unsigned int r[8];
        #pragma unroll
        for (int j = 0; j < 8; ++j) r[j] = f2bf(acc[j]);
        o.x = r[0] | (r[1] << 16);
        o.y = r[2] | (r[3] << 16);
        o.z = r[4] | (r[5] << 16);
        o.w = r[6] | (r[7] << 16);
        *(uint4*)&zout[i * 256 + li * 8] = o;
    }
}

// ---------------------------------------------------------------- u-sums over active set
__global__ __launch_bounds__(256) void u_kernel(
        const unsigned short* __restrict__ z0,  const unsigned short* __restrict__ z11,
        const unsigned short* __restrict__ z12, const unsigned short* __restrict__ z21,
        const unsigned short* __restrict__ z22,
        const float* __restrict__ r1, const float* __restrict__ r2,
        const int* __restrict__ list, const int* __restrict__ nact,
        float* __restrict__ u) {
    int t = threadIdx.x;          // elem 0..255
    int na = *nact;
    const unsigned short* Z[5] = { z0, z11, z12, z21, z22 };
    float acc[20];
    #pragma unroll
    for (int j = 0; j < 20; ++j) acc[j] = 0.f;
    for (int a = blockIdx.x; a < na; a += 64) {
        int n = list[a];
        float w0 = r1[n];
        float w1 = r2[n];
        float w2 = r1[N_NODES + n];
        float w3 = r2[N_NODES + n];
        #pragma unroll
        for (int s = 0; s < 5; ++s) {
            float zv = __uint_as_float(((unsigned int)Z[s][n * 256 + t]) << 16);
            acc[0 * 5 + s] += w0 * zv;
            acc[1 * 5 + s] += w1 * zv;
            acc[2 * 5 + s] += w2 * zv;
            acc[3 * 5 + s] += w3 * zv;
        }
    }
    #pragma unroll
    for (int j = 0; j < 20; ++j)
        if (acc[j] != 0.f) atomicAdd(&u[j * 256 + t], acc[j]);
}

// ---------------------------------------------------------------- final stage 1
// block = (s,g), 25 blocks x 512 thr. Stage W1c_s (32 KB) in LDS via coalesced
// float4 streaming (high MLP), then 64 LDS-FMAs per thread.
// g=0: h0 from z_s[node0]; g=1..4: q_ek from u[ek*5+s]. T[g][b][f1] += dot.
__global__ __launch_bounds__(512) void final_T_kernel(
        const unsigned short* __restrict__ z0,  const unsigned short* __restrict__ z11,
        const unsigned short* __restrict__ z12, const unsigned short* __restrict__ z21,
        const unsigned short* __restrict__ z22,
        const float* __restrict__ u, const float* __restrict__ S,
        const float* __restrict__ W1, const float* __restrict__ b1,
        float* __restrict__ T) {
    __shared__ float Ws[8192];     // 32 KB: W1c_s[f0][f1]
    __shared__ float src[256];     // source vector [b*64+f0]
    int blk = blockIdx.x;
    int s = blk / 5, g = blk - s * 5;
    int t = threadIdx.x;
    const int w1off[5] = { 0, 8192, 16384, 32768, 40960 };
    const float4* wsrc = (const float4*)(W1 + w1off[s]);
    const float4* wsrc0 = (const float4*)(W1 + 24576);     // W1[1,0], added when s==0
    float4* wdst = (float4*)Ws;
    #pragma unroll
    for (int i = 0; i < 4; ++i) {
        float4 v = wsrc[i * 512 + t];
        if (s == 0) {
            float4 v2 = wsrc0[i * 512 + t];
            v.x += v2.x; v.y += v2.y; v.z += v2.z; v.w += v2.w;
        }
        wdst[i * 512 + t] = v;
    }
    if (t < 256) {
        const unsigned short* Z[5] = { z0, z11, z12, z21, z22 };
        float sv;
        if (g == 0) sv = __uint_as_float(((unsigned int)Z[s][t]) << 16);  // node 0
        else        sv = u[((g - 1) * 5 + s) * 256 + t];
        src[t] = sv;
    }
    __syncthreads();
    int b = t >> 7, f1 = t & 127;
    const float* sp = src + b * 64;
    float acc = 0.f;
    #pragma unroll 16
    for (int f0 = 0; f0 < 64; ++f0)
        acc += sp[f0] * Ws[f0 * 128 + f1];
    if (s == 0) acc += (g == 0) ? b1[f1] : S[g - 1] * b1[f1];
    atomicAdd(&T[g * 512 + t], acc);
}

// ---------------------------------------------------------------- final stage 2
// block = g, 5 blocks x 512 thr. Stage W2c_g (64 KB) + T_g (2 KB) in LDS, then
// 128 LDS-FMAs per thread. out[b][f2] += dot.
__global__ __launch_bounds__(512) void final_out_kernel(
        const float* __restrict__ T, const float* __restrict__ W2,
        const float* __restrict__ b2, float* __restrict__ out) {
    __shared__ float Ws[16384];    // 64 KB: W2c_g[f1][f2]
    __shared__ float Ts[512];
    int g = blockIdx.x;
    int t = threadIdx.x;
    const int w2off[5] = { 0, 16384, 32768, 65536, 81920 };  // W2[00],[01],[02],[11],[12]
    const float4* wsrc = (const float4*)(W2 + w2off[g]);
    const float4* wsrc0 = (const float4*)(W2 + 49152);       // W2[1,0], added when g==0
    float4* wdst = (float4*)Ws;
    #pragma unroll
    for (int i = 0; i < 8; ++i) {
        float4 v = wsrc[i * 512 + t];
        if (g == 0) {
            float4 v2 = wsrc0[i * 512 + t];
            v.x += v2.x; v.y += v2.y; v.z += v2.z; v.w += v2.w;
        }
        wdst[i * 512 + t] = v;
    }
    Ts[t] = T[g * 512 + t];
    __syncthreads();
    int b = t >> 7, f2 = t & 127;
    const float* tp = Ts + b * 128;
    float acc = (g == 0) ? b2[f2] : 0.f;
    #pragma unroll 16
    for (int f1 = 0; f1 < 128; ++f1)
        acc += tp[f1] * Ws[f1 * 128 + f2];
    atomicAdd(&out[t], acc);
}

// ----------------------------------------------------------------
extern "C" void kernel_launch(void* const* d_in, const int* in_sizes, int n_in,
                              void* d_out, int out_size, void* d_ws, size_t ws_size,
                              hipStream_t stream) {
    const float* x  = (const float*)d_in[0];
    const int*   ei = (const int*)d_in[1];
    const float* ev = (const float*)d_in[2];
    const float* W1 = (const float*)d_in[3];
    const float* b1 = (const float*)d_in[4];
    const float* W2 = (const float*)d_in[5];
    const float* b2 = (const float*)d_in[6];
    float* out = (float*)d_out;

    char* ws = (char*)d_ws;
    size_t off = 0;
    auto alloc = [&](size_t bytes) { size_t o = off; off += (bytes + 255) & ~(size_t)255; return o; };
    const size_t ZB  = (size_t)N_NODES * BATCH * F0 * 2;      // 5.12 MB per bf16 z buffer
    size_t o_z0   = alloc(ZB);
    size_t o_z11  = alloc(ZB);
    size_t o_z12  = alloc(ZB);
    size_t o_z21  = alloc(ZB);
    size_t o_z22  = alloc(ZB);
    size_t o_cev  = alloc((size_t)NG * N_EDGES * 4);          // packed (bf16 val | u16 col)
    size_t o_slot = alloc((size_t)NG * N_EDGES * 2);          // u16 slots
    size_t o_rs   = alloc((size_t)NG * (N_NODES + 1) * 4);
    size_t o_sup1 = alloc((size_t)NG * N_NODES * 4);
    size_t o_list = alloc((size_t)N_NODES * 4);
    size_t o_zero = off;                                      // zeroed region starts here
    size_t o_cnt   = alloc((size_t)NG * N_NODES * 4);
    size_t o_r     = alloc((size_t)2 * NG * N_NODES * 4);     // r1[2][N] then r2[2][N]
    size_t o_S     = alloc(4 * 4);                            // S1_e0, S2_e0, S1_e1, S2_e1
    size_t o_u     = alloc((size_t)20 * 256 * 4);
    size_t o_T     = alloc((size_t)5 * 512 * 4);
    size_t o_misc  = alloc(3 * 4);                            // ns1[2], nact
    size_t o_aflag = alloc((size_t)N_NODES * 4);
    size_t zero_bytes = off - o_zero;

    unsigned short* z0  = (unsigned short*)(ws + o_z0);
    unsigned short* z11 = (unsigned short*)(ws + o_z11);
    unsigned short* z12 = (unsigned short*)(ws + o_z12);
    unsigned short* z21 = (unsigned short*)(ws + o_z21);
    unsigned short* z22 = (unsigned short*)(ws + o_z22);
    unsigned int*   cev  = (unsigned int*)(ws + o_cev);
    unsigned short* slot = (unsigned short*)(ws + o_slot);
    int*   rs   = (int*)(ws + o_rs);
    int*   sup1 = (int*)(ws + o_sup1);
    int*   list = (int*)(ws + o_list);
    int*   cnt  = (int*)(ws + o_cnt);
    float* r1   = (float*)(ws + o_r);
    float* r2   = r1 + 2 * N_NODES;
    float* S    = (float*)(ws + o_S);
    float* u    = (float*)(ws + o_u);
    float* T    = (float*)(ws + o_T);
    int*   ns1  = (int*)(ws + o_misc);
    int*   nact = ns1 + 2;
    int*   aflag = (int*)(ws + o_aflag);

    hipMemsetAsync(ws + o_zero, 0, zero_bytes, stream);
    hipMemsetAsync(out, 0, 512 * sizeof(float), stream);

    histprep_kernel<<<12500, 256, 0, stream>>>(ei, ev, cnt, slot, r1, S, sup1, ns1,
                                               aflag, list, nact, x, z0);
    prefix_kernel  <<<2,    1024, 0, stream>>>(cnt, rs);
    scatter_kernel <<<2500,  256, 0, stream>>>(ei, ev, rs, slot, cev);
    r2_kernel      <<<16,    256, 0, stream>>>(cev, rs, sup1, ns1, r1, r2, S,
                                               aflag, list, nact);
    spmm_full_kernel<<<10000, 256, 0, stream>>>(cev, rs, z0, z11, z21);
    spmm_act_kernel<<<5000,  256, 0, stream>>>(cev, rs, z11, z21, z12, z22, list, nact);
    u_kernel       <<<64,    256, 0, stream>>>(z0, z11, z12, z21, z22, r1, r2, list, nact, u);
    final_T_kernel <<<25,    512, 0, stream>>>(z0, z11, z12, z21, z22, u, S, W1, b1, T);
    final_out_kernel<<<5,    512, 0, stream>>>(T, W2, b2, out);
}

// Round 10
// 217.685 us; speedup vs baseline: 1.3553x; 1.0544x over previous
//
#include <hip/hip_runtime.h>

#define N_NODES 10000
#define N_EDGES 320000
#define NG      2
#define BATCH   4
#define F0      64
#define F1      128
#define F2      128
// z layout: [node][B*F0=256] bf16 (512 B/node). No h matrix: layer-2 done in
// u-space: u[ek][s][256] = sum_n r_ek[n] * z_s[n], q_ek = sum_s u W1c_s + S_ek b1.

__device__ __forceinline__ unsigned short f2bf(float x) {
    unsigned int u = __float_as_uint(x);
    unsigned int r = (u + 0x7fff + ((u >> 16) & 1)) >> 16;   // RNE
    return (unsigned short)r;
}
__device__ __forceinline__ float bflo(unsigned int u) { return __uint_as_float(u << 16); }
__device__ __forceinline__ float bfhi(unsigned int u) { return __uint_as_float(u & 0xffff0000u); }

// ---------------------------------------------------------------- pass 1 (fused)
// blocks [0,2500):    hist + slot(u16) + r1 + S1 + supp(r1)->active push
// blocks [2500,12500): x[B,N,F0] fp32 -> z0[N,256] bf16
__global__ void histprep_kernel(const int* __restrict__ ei, const float* __restrict__ ev,
                                int* __restrict__ cnt, unsigned short* __restrict__ slot,
                                float* __restrict__ r1, float* __restrict__ S,
                                int* __restrict__ aflag, int* __restrict__ list,
                                int* __restrict__ nact,
                                const float* __restrict__ x, unsigned short* __restrict__ z0) {
    int blk = blockIdx.x;
    if (blk < 2500) {
        int j = blk * 256 + threadIdx.x;
        if (j == 0) {       // force node 0 active (finals need z_s[0])
            if (atomicExch(&aflag[0], 1) == 0) { int p = atomicAdd(nact, 1); list[p] = 0; }
        }
        int e = j / N_EDGES, t = j - e * N_EDGES;
        int r = ei[e * 2 * N_EDGES + t];
        slot[j] = (unsigned short)atomicAdd(&cnt[e * N_NODES + r], 1);
        if (r == 0) {
            int c = ei[e * 2 * N_EDGES + N_EDGES + t];
            float v = ev[e * N_EDGES + t];
            float old = atomicAdd(&r1[e * N_NODES + c], v);
            atomicAdd(&S[e * 2], v);
            if (old == 0.f && v != 0.f) {
                if (atomicExch(&aflag[c], 1) == 0) { int q = atomicAdd(nact, 1); list[q] = c; }
            }
        }
    } else {
        int idx = (blk - 2500) * 256 + threadIdx.x;   // covers N*B*F0 exactly
        int n = idx >> 8, rem = idx & 255, b = rem >> 6, f = rem & 63;
        z0[idx] = f2bf(x[b * (N_NODES * F0) + n * F0 + f]);
    }
}

// ---------------------------------------------------------------- pass 2: prefix scan
__global__ __launch_bounds__(1024) void prefix_kernel(const int* __restrict__ cnt,
                                                      int* __restrict__ rs) {
    __shared__ int wtot[16];
    int e = blockIdx.x, t = threadIdx.x;
    int lane = t & 63, w = t >> 6;
    int i0 = t * 10;
    int c[10];
    int local = 0;
    #pragma unroll
    for (int j = 0; j < 10; ++j) {
        int i = i0 + j;
        int v = (i < N_NODES) ? cnt[e * N_NODES + i] : 0;
        c[j] = local;
        local += v;
    }
    int inc = local;
    #pragma unroll
    for (int off = 1; off < 64; off <<= 1) {
        int u = __shfl_up(inc, off);
        if (lane >= off) inc += u;
    }
    if (lane == 63) wtot[w] = inc;
    __syncthreads();
    int base = 0;
    for (int k = 0; k < w; ++k) base += wtot[k];
    int excl = base + inc - local;
    #pragma unroll
    for (int j = 0; j < 10; ++j) {
        int i = i0 + j;
        if (i < N_NODES) rs[e * (N_NODES + 1) + i] = excl + c[j];
    }
    if (t == 1023) {
        int grand = 0;
        #pragma unroll
        for (int k = 0; k < 16; ++k) grand += wtot[k];
        rs[e * (N_NODES + 1) + N_NODES] = grand;
    }
}

// ---------------------------------------------------------------- pass 3: scatter + r2 + list
// packed 4 B entry: (bf16(val) << 16) | col. r1 is 80 KB -> L1/L2-resident, so
// the per-edge r1[r] lookup is cheap; r2/S2/active-list built here (fp32 vals).
__global__ void scatter_kernel(const int* __restrict__ ei, const float* __restrict__ ev,
                               const int* __restrict__ rs, const unsigned short* __restrict__ slot,
                               const float* __restrict__ r1,
                               unsigned int* __restrict__ cev,
                               float* __restrict__ r2, float* __restrict__ S,
                               int* __restrict__ aflag, int* __restrict__ list,
                               int* __restrict__ nact) {
    int j = blockIdx.x * 256 + threadIdx.x;
    if (j >= NG * N_EDGES) return;
    int e = j / N_EDGES, t = j - e * N_EDGES;
    int r = ei[e * 2 * N_EDGES + t];
    int c = ei[e * 2 * N_EDGES + N_EDGES + t];
    float v = ev[e * N_EDGES + t];
    int pos = rs[e * (N_NODES + 1) + r] + (int)slot[j];
    cev[e * N_EDGES + pos] = ((unsigned int)f2bf(v) << 16) | (unsigned int)c;
    float w = r1[e * N_NODES + r];
    float add = w * v;
    if (add != 0.f) {
        float old = atomicAdd(&r2[e * N_NODES + c], add);
        atomicAdd(&S[e * 2 + 1], add);
        if (old == 0.f) {
            if (atomicExch(&aflag[c], 1) == 0) {
                int q = atomicAdd(nact, 1);
                list[q] = c;
            }
        }
    }
}

// ---------------------------------------------------------------- SpMM tap-1 (full, half-split)
__global__ __launch_bounds__(256) void spmm_full_kernel(
        const unsigned int* __restrict__ cev, const int* __restrict__ rs,
        const unsigned short* __restrict__ z0,
        unsigned short* __restrict__ z11, unsigned short* __restrict__ z21) {
    int blk = blockIdx.x;
    int m8 = blk & 7;
    int h = (m8 < 4) ? 0 : 1;
    int grp = (blk >> 3) * 4 + (m8 & 3);     // 0..4999 within this half
    int t = threadIdx.x;
    int w = t >> 6, l = t & 63;
    int rid = grp * 4 + w;                   // 0..19999
    int e = (rid >= N_NODES) ? 1 : 0;
    int i = rid - e * N_NODES;
    unsigned short* zout = e ? z21 : z11;
    const unsigned int* cv = cev + e * N_EDGES;
    int s    = rs[e * (N_NODES + 1) + i];
    int send = rs[e * (N_NODES + 1) + i + 1];
    int sl = l >> 4, li = l & 15;
    int eoff = h * 128 + li * 8;
    float acc[8];
    #pragma unroll
    for (int j = 0; j < 8; ++j) acc[j] = 0.f;

    int p = s + sl;
    for (; p + 4 < send; p += 8) {
        unsigned int u0 = cv[p];
        unsigned int u1 = cv[p + 4];
        int c0 = u0 & 0xffff; float v0 = bfhi(u0);
        int c1 = u1 & 0xffff; float v1 = bfhi(u1);
        uint4 za = *(const uint4*)&z0[c0 * 256 + eoff];
        uint4 zb = *(const uint4*)&z0[c1 * 256 + eoff];
        acc[0] += v0 * bflo(za.x) + v1 * bflo(zb.x);
        acc[1] += v0 * bfhi(za.x) + v1 * bfhi(zb.x);
        acc[2] += v0 * bflo(za.y) + v1 * bflo(zb.y);
        acc[3] += v0 * bfhi(za.y) + v1 * bfhi(zb.y);
        acc[4] += v0 * bflo(za.z) + v1 * bflo(zb.z);
        acc[5] += v0 * bfhi(za.z) + v1 * bfhi(zb.z);
        acc[6] += v0 * bflo(za.w) + v1 * bflo(zb.w);
        acc[7] += v0 * bfhi(za.w) + v1 * bfhi(zb.w);
    }
    for (; p < send; p += 4) {
        unsigned int u0 = cv[p];
        int c0 = u0 & 0xffff; float v0 = bfhi(u0);
        uint4 za = *(const uint4*)&z0[c0 * 256 + eoff];
        acc[0] += v0 * bflo(za.x); acc[1] += v0 * bfhi(za.x);
        acc[2] += v0 * bflo(za.y); acc[3] += v0 * bfhi(za.y);
        acc[4] += v0 * bflo(za.z); acc[5] += v0 * bfhi(za.z);
        acc[6] += v0 * bflo(za.w); acc[7] += v0 * bfhi(za.w);
    }
    #pragma unroll
    for (int j = 0; j < 8; ++j) {
        acc[j] += __shfl_xor(acc[j], 16);
        acc[j] += __shfl_xor(acc[j], 32);
    }
    if (l < 16) {
        uint4 o;
        unsigned int r[8];
        #pragma unroll
        for (int j = 0; j < 8; ++j) r[j] = f2bf(acc[j]);
        o.x = r[0] | (r[1] << 16);
        o.y = r[2] | (r[3] << 16);
        o.z = r[4] | (r[5] << 16);
        o.w = r[6] | (r[7] << 16);
        *(uint4*)&zout[i * 256 + h * 128 + l * 8] = o;
    }
}

// ---------------------------------------------------------------- SpMM tap-2 (active rows only)
__global__ __launch_bounds__(256) void spmm_act_kernel(
        const unsigned int* __restrict__ cev, const int* __restrict__ rs,
        const unsigned short* __restrict__ zin0, const unsigned short* __restrict__ zin1,
        unsigned short* __restrict__ zout0, unsigned short* __restrict__ zout1,
        const int* __restrict__ list, const int* __restrict__ nact) {
    int t = threadIdx.x;
    int w = t >> 6, l = t & 63;
    int rid = blockIdx.x * 4 + w;
    int na = *nact;
    if (rid >= 2 * na) return;
    int e = (rid >= na) ? 1 : 0;
    int i = list[rid - e * na];
    const unsigned short* zin = e ? zin1 : zin0;
    unsigned short* zout = e ? zout1 : zout0;
    const unsigned int* cv = cev + e * N_EDGES;
    int s    = rs[e * (N_NODES + 1) + i];
    int send = rs[e * (N_NODES + 1) + i + 1];
    int hf = l >> 5, li = l & 31;
    float acc[8];
    #pragma unroll
    for (int j = 0; j < 8; ++j) acc[j] = 0.f;

    int p = s + hf;
    for (; p + 2 < send; p += 4) {
        unsigned int u0 = cv[p];
        unsigned int u1 = cv[p + 2];
        int c0 = u0 & 0xffff; float v0 = bfhi(u0);
        int c1 = u1 & 0xffff; float v1 = bfhi(u1);
        uint4 za = *(const uint4*)&zin[c0 * 256 + li * 8];
        uint4 zb = *(const uint4*)&zin[c1 * 256 + li * 8];
        acc[0] += v0 * bflo(za.x) + v1 * bflo(zb.x);
        acc[1] += v0 * bfhi(za.x) + v1 * bfhi(zb.x);
        acc[2] += v0 * bflo(za.y) + v1 * bflo(zb.y);
        acc[3] += v0 * bfhi(za.y) + v1 * bfhi(zb.y);
        acc[4] += v0 * bflo(za.z) + v1 * bflo(zb.z);
        acc[5] += v0 * bfhi(za.z) + v1 * bfhi(zb.z);
        acc[6] += v0 * bflo(za.w) + v1 * bflo(zb.w);
        acc[7] += v0 * bfhi(za.w) + v1 * bfhi(zb.w);
    }
    for (; p < send; p += 2) {
        unsigned int u0 = cv[p];
        int c0 = u0 & 0xffff; float v0 = bfhi(u0);
        uint4 za = *(const uint4*)&zin[c0 * 256 + li * 8];
        acc[0] += v0 * bflo(za.x); acc[1] += v0 * bfhi(za.x);
        acc[2] += v0 * bflo(za.y); acc[3] += v0 * bfhi(za.y);
        acc[4] += v0 * bflo(za.z); acc[5] += v0 * bfhi(za.z);
        acc[6] += v0 * bflo(za.w); acc[7] += v0 * bfhi(za.w);
    }
    #pragma unroll
    for (int j = 0; j < 8; ++j) acc[j] += __shfl_xor(acc[j], 32);
    if (hf == 0) {
        uint4 o;
        unsigned int r[8];
        #pragma unroll
        for (int j = 0; j < 8; ++j) r[j] = f2bf(acc[j]);
        o.x = r[0] | (r[1] << 16);
        o.y = r[2] | (r[3] << 16);
        o.z = r[4] | (r[5] << 16);
        o.w = r[6] | (r[7] << 16);
        *(uint4*)&zout[i * 256 + li * 8] = o;
    }
}

// ---------------------------------------------------------------- u-sums over active set
__global__ __launch_bounds__(256) void u_kernel(
        const unsigned short* __restrict__ z0,  const unsigned short* __restrict__ z11,
        const unsigned short* __restrict__ z12, const unsigned short* __restrict__ z21,
        const unsigned short* __restrict__ z22,
        const float* __restrict__ r1, const float* __restrict__ r2,
        const int* __restrict__ list, const int* __restrict__ nact,
        float* __restrict__ u) {
    int t = threadIdx.x;          // elem 0..255
    int na = *nact;
    const unsigned short* Z[5] = { z0, z11, z12, z21, z22 };
    float acc[20];
    #pragma unroll
    for (int j = 0; j < 20; ++j) acc[j] = 0.f;
    for (int a = blockIdx.x; a < na; a += 64) {
        int n = list[a];
        float w0 = r1[n];
        float w1 = r2[n];
        float w2 = r1[N_NODES + n];
        float w3 = r2[N_NODES + n];
        #pragma unroll
        for (int s = 0; s < 5; ++s) {
            float zv = __uint_as_float(((unsigned int)Z[s][n * 256 + t]) << 16);
            acc[0 * 5 + s] += w0 * zv;
            acc[1 * 5 + s] += w1 * zv;
            acc[2 * 5 + s] += w2 * zv;
            acc[3 * 5 + s] += w3 * zv;
        }
    }
    #pragma unroll
    for (int j = 0; j < 20; ++j)
        if (acc[j] != 0.f) atomicAdd(&u[j * 256 + t], acc[j]);
}

// ---------------------------------------------------------------- final stage 1
// block = (s,g), 25 blocks x 512 thr. W1c_s (32 KB) staged in LDS (coalesced
// float4, high MLP), then 64 LDS-FMAs/thread. Block 0 also zeroes out[512].
__global__ __launch_bounds__(512) void final_T_kernel(
        const unsigned short* __restrict__ z0,  const unsigned short* __restrict__ z11,
        const unsigned short* __restrict__ z12, const unsigned short* __restrict__ z21,
        const unsigned short* __restrict__ z22,
        const float* __restrict__ u, const float* __restrict__ S,
        const float* __restrict__ W1, const float* __restrict__ b1,
        float* __restrict__ T, float* __restrict__ out) {
    __shared__ float Ws[8192];     // 32 KB: W1c_s[f0][f1]
    __shared__ float src[256];     // source vector [b*64+f0]
    int blk = blockIdx.x;
    int s = blk / 5, g = blk - s * 5;
    int t = threadIdx.x;
    if (blk == 0) out[t] = 0.f;    // zero d_out (poisoned by harness)
    const int w1off[5] = { 0, 8192, 16384, 32768, 40960 };
    const float4* wsrc = (const float4*)(W1 + w1off[s]);
    const float4* wsrc0 = (const float4*)(W1 + 24576);     // W1[1,0], added when s==0
    float4* wdst = (float4*)Ws;
    #pragma unroll
    for (int i = 0; i < 4; ++i) {
        float4 v = wsrc[i * 512 + t];
        if (s == 0) {
            float4 v2 = wsrc0[i * 512 + t];
            v.x += v2.x; v.y += v2.y; v.z += v2.z; v.w += v2.w;
        }
        wdst[i * 512 + t] = v;
    }
    if (t < 256) {
        const unsigned short* Z[5] = { z0, z11, z12, z21, z22 };
        float sv;
        if (g == 0) sv = __uint_as_float(((unsigned int)Z[s][t]) << 16);  // node 0
        else        sv = u[((g - 1) * 5 + s) * 256 + t];
        src[t] = sv;
    }
    __syncthreads();
    int b = t >> 7, f1 = t & 127;
    const float* sp = src + b * 64;
    float acc = 0.f;
    #pragma unroll 16
    for (int f0 = 0; f0 < 64; ++f0)
        acc += sp[f0] * Ws[f0 * 128 + f1];
    if (s == 0) acc += (g == 0) ? b1[f1] : S[g - 1] * b1[f1];
    atomicAdd(&T[g * 512 + t], acc);
}

// ---------------------------------------------------------------- final stage 2
// block = g, 5 blocks x 512 thr. W2c_g (64 KB) + T_g staged in LDS, then
// 128 LDS-FMAs/thread. out[b][f2] += dot (out zeroed by final_T blk 0).
__global__ __launch_bounds__(512) void final_out_kernel(
        const float* __restrict__ T, const float* __restrict__ W2,
        const float* __restrict__ b2, float* __restrict__ out) {
    __shared__ float Ws[16384];    // 64 KB: W2c_g[f1][f2]
    __shared__ float Ts[512];
    int g = blockIdx.x;
    int t = threadIdx.x;
    const int w2off[5] = { 0, 16384, 32768, 65536, 81920 };  // W2[00],[01],[02],[11],[12]
    const float4* wsrc = (const float4*)(W2 + w2off[g]);
    const float4* wsrc0 = (const float4*)(W2 + 49152);       // W2[1,0], added when g==0
    float4* wdst = (float4*)Ws;
    #pragma unroll
    for (int i = 0; i < 8; ++i) {
        float4 v = wsrc[i * 512 + t];
        if (g == 0) {
            float4 v2 = wsrc0[i * 512 + t];
            v.x += v2.x; v.y += v2.y; v.z += v2.z; v.w += v2.w;
        }
        wdst[i * 512 + t] = v;
    }
    Ts[t] = T[g * 512 + t];
    __syncthreads();
    int b = t >> 7, f2 = t & 127;
    const float* tp = Ts + b * 128;
    float acc = (g == 0) ? b2[f2] : 0.f;
    #pragma unroll 16
    for (int f1 = 0; f1 < 128; ++f1)
        acc += tp[f1] * Ws[f1 * 128 + f2];
    atomicAdd(&out[t], acc);
}

// ----------------------------------------------------------------
extern "C" void kernel_launch(void* const* d_in, const int* in_sizes, int n_in,
                              void* d_out, int out_size, void* d_ws, size_t ws_size,
                              hipStream_t stream) {
    const float* x  = (const float*)d_in[0];
    const int*   ei = (const int*)d_in[1];
    const float* ev = (const float*)d_in[2];
    const float* W1 = (const float*)d_in[3];
    const float* b1 = (const float*)d_in[4];
    const float* W2 = (const float*)d_in[5];
    const float* b2 = (const float*)d_in[6];
    float* out = (float*)d_out;

    char* ws = (char*)d_ws;
    size_t off = 0;
    auto alloc = [&](size_t bytes) { size_t o = off; off += (bytes + 255) & ~(size_t)255; return o; };
    const size_t ZB  = (size_t)N_NODES * BATCH * F0 * 2;      // 5.12 MB per bf16 z buffer
    size_t o_z0   = alloc(ZB);
    size_t o_z11  = alloc(ZB);
    size_t o_z12  = alloc(ZB);
    size_t o_z21  = alloc(ZB);
    size_t o_z22  = alloc(ZB);
    size_t o_cev  = alloc((size_t)NG * N_EDGES * 4);          // packed (bf16 val | u16 col)
    size_t o_slot = alloc((size_t)NG * N_EDGES * 2);          // u16 slots
    size_t o_rs   = alloc((size_t)NG * (N_NODES + 1) * 4);
    size_t o_list = alloc((size_t)N_NODES * 4);
    size_t o_zero = off;                                      // zeroed region starts here
    size_t o_cnt   = alloc((size_t)NG * N_NODES * 4);
    size_t o_r     = alloc((size_t)2 * NG * N_NODES * 4);     // r1[2][N] then r2[2][N]
    size_t o_S     = alloc(4 * 4);                            // S1_e0, S2_e0, S1_e1, S2_e1
    size_t o_u     = alloc((size_t)20 * 256 * 4);
    size_t o_T     = alloc((size_t)5 * 512 * 4);
    size_t o_misc  = alloc(4);                                // nact
    size_t o_aflag = alloc((size_t)N_NODES * 4);
    size_t zero_bytes = off - o_zero;

    unsigned short* z0  = (unsigned short*)(ws + o_z0);
    unsigned short* z11 = (unsigned short*)(ws + o_z11);
    unsigned short* z12 = (unsigned short*)(ws + o_z12);
    unsigned short* z21 = (unsigned short*)(ws + o_z21);
    unsigned short* z22 = (unsigned short*)(ws + o_z22);
    unsigned int*   cev  = (unsigned int*)(ws + o_cev);
    unsigned short* slot = (unsigned short*)(ws + o_slot);
    int*   rs   = (int*)(ws + o_rs);
    int*   list = (int*)(ws + o_list);
    int*   cnt  = (int*)(ws + o_cnt);
    float* r1   = (float*)(ws + o_r);
    float* r2   = r1 + 2 * N_NODES;
    float* S    = (float*)(ws + o_S);
    float* u    = (float*)(ws + o_u);
    float* T    = (float*)(ws + o_T);
    int*   nact = (int*)(ws + o_misc);
    int*   aflag = (int*)(ws + o_aflag);

    hipMemsetAsync(ws + o_zero, 0, zero_bytes, stream);

    histprep_kernel<<<12500, 256, 0, stream>>>(ei, ev, cnt, slot, r1, S,
                                               aflag, list, nact, x, z0);
    prefix_kernel  <<<2,    1024, 0, stream>>>(cnt, rs);
    scatter_kernel <<<2500,  256, 0, stream>>>(ei, ev, rs, slot, r1, cev,
                                               r2, S, aflag, list, nact);
    spmm_full_kernel<<<10000, 256, 0, stream>>>(cev, rs, z0, z11, z21);
    spmm_act_kernel<<<5000,  256, 0, stream>>>(cev, rs, z11, z21, z12, z22, list, nact);
    u_kernel       <<<64,    256, 0, stream>>>(z0, z11, z12, z21, z22, r1, r2, list, nact, u);
    final_T_kernel <<<25,    512, 0, stream>>>(z0, z11, z12, z21, z22, u, S, W1, b1, T, out);
    final_out_kernel<<<5,    512, 0, stream>>>(T, W2, b2, out);
}